// Round 2
// baseline (5938.529 us; speedup 1.0000x reference)
//
#include <hip/hip_runtime.h>
#include <hip/hip_bf16.h>
#include <cstdint>

// ---------------------------------------------------------------------------
// Model constants (from reference): B=2 S=2048 D=512 H=8 HD=64, FFH=1024
// Encoder: 4 layers, G=2 groups of Sg=2048 (block-causal-64 + doc mask)
// Router:  2 layers, G=64 groups of Sg=72 (64 tokens + 8 router tokens, full attn)
// Dtypes per reference: ALL float tensors are float32; doc is int32.
// Round 2: fix dtype misread (round 1 read f32 as bf16 -> NaN). fp32 compute.
// ---------------------------------------------------------------------------

__device__ __forceinline__ float wave_sum64(float v) {
#pragma unroll
    for (int o = 32; o; o >>= 1) v += __shfl_xor(v, o);
    return v;
}
__device__ __forceinline__ float wave_max64(float v) {
#pragma unroll
    for (int o = 32; o; o >>= 1) v = fmaxf(v, __shfl_xor(v, o));
    return v;
}

// ---- f32 copy (input x -> mutable X) --------------------------------------
__global__ void copy_in_kernel(const float* __restrict__ src,
                               float* __restrict__ dst, int n) {
    int i = blockIdx.x * 256 + threadIdx.x;
    if (i < n) dst[i] = src[i];
}

// ---- RMSNorm over D=512 ---------------------------------------------------
__global__ __launch_bounds__(256) void rmsnorm_kernel(const float* __restrict__ X,
        const float* __restrict__ W, float* __restrict__ XN) {
    int t = blockIdx.x, tid = threadIdx.x;
    const float* xr = X + (size_t)t * 512;
    float v0 = xr[tid], v1 = xr[tid + 256];
    float ss = wave_sum64(v0 * v0 + v1 * v1);
    __shared__ float red[4];
    if ((tid & 63) == 0) red[tid >> 6] = ss;
    __syncthreads();
    float tot = red[0] + red[1] + red[2] + red[3];
    float scale = rsqrtf(tot * (1.0f / 512.0f) + 1e-6f);
    float* xo = XN + (size_t)t * 512;
    xo[tid]       = v0 * scale * W[tid];
    xo[tid + 256] = v1 * scale * W[tid + 256];
}

// ---- fp32 tiled GEMM: C[M,N] = A[M,K] @ B[K,N] (+ Res) --------------------
// 64x64 tile, BK=16, 256 threads, 4x4 micro-tile. M,N %64==0, K %16==0.
__global__ __launch_bounds__(256) void gemm_kernel(const float* __restrict__ A,
        const float* __restrict__ B, const float* __restrict__ Res,
        float* __restrict__ C, int M, int N, int K) {
    __shared__ float As[16][64];   // [k][m]
    __shared__ float Bs[16][64];   // [k][n]
    int tid = threadIdx.x;
    int tx = tid & 15, ty = tid >> 4;
    int n0 = blockIdx.x * 64, m0 = blockIdx.y * 64;
    int ar = tid >> 2, ac = (tid & 3) * 4;   // A tile: row 0..63, k 0,4,8,12
    int br = tid >> 4, bc = (tid & 15) * 4;  // B tile: k 0..15, col 0..60
    float acc[4][4] = {};
    const float* Aptr = A + (size_t)(m0 + ar) * K + ac;
    const float* Bptr = B + (size_t)br * N + n0 + bc;
    for (int k0 = 0; k0 < K; k0 += 16) {
        float4 av = *reinterpret_cast<const float4*>(Aptr + k0);
        float4 bv = *reinterpret_cast<const float4*>(Bptr + (size_t)k0 * N);
        __syncthreads();
        As[ac + 0][ar] = av.x; As[ac + 1][ar] = av.y;
        As[ac + 2][ar] = av.z; As[ac + 3][ar] = av.w;
        *reinterpret_cast<float4*>(&Bs[br][bc]) = bv;
        __syncthreads();
#pragma unroll
        for (int k = 0; k < 16; ++k) {
            float4 a = *reinterpret_cast<const float4*>(&As[k][ty * 4]);
            float4 b = *reinterpret_cast<const float4*>(&Bs[k][tx * 4]);
            acc[0][0] = fmaf(a.x, b.x, acc[0][0]);
            acc[0][1] = fmaf(a.x, b.y, acc[0][1]);
            acc[0][2] = fmaf(a.x, b.z, acc[0][2]);
            acc[0][3] = fmaf(a.x, b.w, acc[0][3]);
            acc[1][0] = fmaf(a.y, b.x, acc[1][0]);
            acc[1][1] = fmaf(a.y, b.y, acc[1][1]);
            acc[1][2] = fmaf(a.y, b.z, acc[1][2]);
            acc[1][3] = fmaf(a.y, b.w, acc[1][3]);
            acc[2][0] = fmaf(a.z, b.x, acc[2][0]);
            acc[2][1] = fmaf(a.z, b.y, acc[2][1]);
            acc[2][2] = fmaf(a.z, b.z, acc[2][2]);
            acc[2][3] = fmaf(a.z, b.w, acc[2][3]);
            acc[3][0] = fmaf(a.w, b.x, acc[3][0]);
            acc[3][1] = fmaf(a.w, b.y, acc[3][1]);
            acc[3][2] = fmaf(a.w, b.z, acc[3][2]);
            acc[3][3] = fmaf(a.w, b.w, acc[3][3]);
        }
    }
#pragma unroll
    for (int i = 0; i < 4; ++i) {
        size_t off = (size_t)(m0 + ty * 4 + i) * N + n0 + tx * 4;
        float4 o = make_float4(acc[i][0], acc[i][1], acc[i][2], acc[i][3]);
        if (Res) {
            float4 r = *reinterpret_cast<const float4*>(Res + off);
            o.x += r.x; o.y += r.y; o.z += r.z; o.w += r.w;
        }
        *reinterpret_cast<float4*>(C + off) = o;
    }
}

// ---- split qkv + RoPE + transpose to (g,h,s,hd) ---------------------------
__global__ void rope_pack_kernel(const float* __restrict__ QKV, float* __restrict__ Q,
        float* __restrict__ K, float* __restrict__ V, int Sg, int total) {
    int idx = blockIdx.x * 256 + threadIdx.x;
    if (idx >= total) return;
    int i = idx & 31;
    int h = (idx >> 5) & 7;
    int t = idx >> 8;
    int g = t / Sg; int s = t - g * Sg;
    const float* row = QKV + (size_t)t * 1536;
    float inv = powf(10000.0f, -(float)(2 * i) / 64.0f);
    float sn, cs;
    sincosf((float)s * inv, &sn, &cs);
    size_t ob = ((size_t)(g * 8 + h) * Sg + s) * 64 + i;
    int c = h * 64 + i;
    float q1 = row[c], q2 = row[c + 32];
    Q[ob]      = q1 * cs + q2 * sn;
    Q[ob + 32] = q2 * cs - q1 * sn;
    float k1 = row[512 + c], k2 = row[512 + c + 32];
    K[ob]      = k1 * cs + k2 * sn;
    K[ob + 32] = k2 * cs - k1 * sn;
    V[ob]      = row[1024 + c];
    V[ob + 32] = row[1024 + c + 32];
}

// ---- attention: one wave per (g,h,q) row; two-pass online softmax ---------
__device__ __forceinline__ float dot64(const float4* qs4, const float* Krow) {
    const float4* kp = reinterpret_cast<const float4*>(Krow);
    float s = 0.f;
#pragma unroll
    for (int u = 0; u < 16; ++u) {
        float4 kv = kp[u]; float4 qv = qs4[u];
        s = fmaf(qv.x, kv.x, s); s = fmaf(qv.y, kv.y, s);
        s = fmaf(qv.z, kv.z, s); s = fmaf(qv.w, kv.w, s);
    }
    return s;
}

template <bool MASKED, bool TAIL>
__global__ __launch_bounds__(64) void attn_kernel(const float* __restrict__ Q,
        const float* __restrict__ K, const float* __restrict__ V,
        const int* __restrict__ doc, float* __restrict__ AO, int Sg) {
    int lane = threadIdx.x;
    int idx = blockIdx.x;
    int q = idx % Sg; int gh = idx / Sg; int g = gh >> 3;
    const float* Kb = K + (size_t)gh * Sg * 64;
    const float* Vb = V + (size_t)gh * Sg * 64;
    __shared__ float qs[64];
    __shared__ float ps[64];
    qs[lane] = Q[((size_t)gh * Sg + q) * 64 + lane] * 0.125f; // pre-scale by 1/sqrt(64)
    __syncthreads();
    const float4* qs4 = reinterpret_cast<const float4*>(qs);
    const int* docb = nullptr; int mydoc = 0;
    if (MASKED) { docb = doc + (size_t)g * Sg; mydoc = docb[q]; }
    int kblocks = MASKED ? ((q >> 6) + 1) : ((Sg + 63) >> 6);
    float m_i = -1e30f, l_i = 0.f;
    for (int kk = 0; kk < kblocks; ++kk) {
        int kidx = kk * 64 + lane;
        bool ok = (!TAIL) || (kidx < Sg);
        if (MASKED && ok) ok = (docb[kidx] == mydoc);
        if (ok) {
            float s = dot64(qs4, Kb + (size_t)kidx * 64);
            float mn = fmaxf(m_i, s);
            l_i = l_i * __expf(m_i - mn) + __expf(s - mn);
            m_i = mn;
        }
    }
    float Mx = wave_max64(m_i);
    float L = wave_sum64(l_i * __expf(m_i - Mx));
    float invL = 1.0f / L;
    float o_acc = 0.f;
    for (int kk = 0; kk < kblocks; ++kk) {
        int kidx = kk * 64 + lane;
        bool ok = (!TAIL) || (kidx < Sg);
        if (MASKED && ok) ok = (docb[kidx] == mydoc);
        float p = 0.f;
        if (ok) p = __expf(dot64(qs4, Kb + (size_t)kidx * 64) - Mx);
        __syncthreads();
        ps[lane] = p;
        __syncthreads();
        const float* vcol = Vb + (size_t)kk * 64 * 64 + lane;
        int lim = TAIL ? ((Sg - kk * 64) < 64 ? (Sg - kk * 64) : 64) : 64;
        for (int src = 0; src < lim; ++src)
            o_acc = fmaf(ps[src], vcol[(size_t)src * 64], o_acc);
    }
    AO[((size_t)g * Sg + q) * 512 + ((gh & 7) * 64) + lane] = o_acc * invL;
}

// ---- silu(h1)*h2 ----------------------------------------------------------
__global__ void silu_mul_kernel(const float* __restrict__ H, float* __restrict__ Mid, int total) {
    int idx = blockIdx.x * 256 + threadIdx.x;
    if (idx >= total) return;
    int t = idx >> 10, j = idx & 1023;
    float a = H[(size_t)t * 2048 + j];
    float b = H[(size_t)t * 2048 + 1024 + j];
    Mid[idx] = (a / (1.0f + __expf(-a))) * b;
}

// ---- build router stream: (64 groups) x (64 tokens + 8 router tokens) -----
__global__ void router_build_kernel(const float* __restrict__ X,
        const float* __restrict__ RT, float* __restrict__ X2, int total) {
    int idx = blockIdx.x * 256 + threadIdx.x;
    if (idx >= total) return;
    int d = idx & 511;
    int p = (idx >> 9) % 72;
    int g2 = idx / (72 * 512);
    X2[idx] = (p < 64) ? X[((size_t)g2 * 64 + p) * 512 + d]
                       : RT[(p - 64) * 512 + d];
}

// ---- gather xr[:,64:72,:] into dense (512,512) ----------------------------
__global__ void gather_rows_kernel(const float* __restrict__ X2, float* __restrict__ RR, int total) {
    int idx = blockIdx.x * 256 + threadIdx.x;
    if (idx >= total) return;
    int d = idx & 511;
    int row = idx >> 9;
    int g2 = row >> 3, rr = row & 7;
    RR[idx] = X2[((size_t)(g2 * 72 + 64 + rr)) * 512 + d];
}

// ---- l2-normalize each 128-half of each out row (l2n commutes w/ expand) --
__global__ __launch_bounds__(64) void norm_half_kernel(const float* __restrict__ IN,
        float* __restrict__ OUT) {
    int b = blockIdx.x; int lane = threadIdx.x;
    size_t base = (size_t)(b >> 1) * 256 + (size_t)(b & 1) * 128;
    float v0 = IN[base + lane], v1 = IN[base + 64 + lane];
    float ss = wave_sum64(v0 * v0 + v1 * v1);
    float sc = 1.0f / fmaxf(sqrtf(ss), 1e-12f);
    OUT[base + lane]      = v0 * sc;
    OUT[base + 64 + lane] = v1 * sc;
}

// ---- l2-normalize key columns: keys (32,128,16) over d --------------------
__global__ __launch_bounds__(64) void norm_keys_kernel(const float* __restrict__ Kin,
        float* __restrict__ Kout) {
    int b = blockIdx.x; int lane = threadIdx.x;
    int g = b >> 4, e = b & 15;
    size_t base = (size_t)g * 2048 + e;
    float v0 = Kin[base + (size_t)lane * 16];
    float v1 = Kin[base + (size_t)(lane + 64) * 16];
    float ss = wave_sum64(v0 * v0 + v1 * v1);
    float sc = 1.0f / fmaxf(sqrtf(ss), 1e-12f);
    Kout[base + (size_t)lane * 16]        = v0 * sc;
    Kout[base + (size_t)(lane + 64) * 16] = v1 * sc;
}

// ---- logits + top2 (stable, jax tie-break) --------------------------------
__global__ __launch_bounds__(64) void logits_top2_kernel(const float* __restrict__ OUTN,
        const float* __restrict__ KRN, const float* __restrict__ KGN,
        float* __restrict__ out) {
    int blk = blockIdx.x;
    int g = blk >> 6, bcol = blk & 63;
    int b = bcol >> 5, l = bcol & 31;
    int lsrc = (l + 31) & 31;     // roll(+1): element l comes from l-1
    int r = g >> 2;               // repeat RM=4
    int row = (b * 32 + lsrc) * 8 + r;
    const float* rvec = OUTN + (size_t)row * 256;
    __shared__ float sc[32];
    int lane = threadIdx.x;
    if (lane < 32) {
        int e = lane & 15;
        const float* kb = ((lane < 16) ? KRN : KGN) + (size_t)g * 2048 + e;
        const float* xv = (lane < 16) ? rvec : (rvec + 128);
        float s = 0.f;
#pragma unroll 8
        for (int d = 0; d < 128; ++d) s = fmaf(xv[d], kb[(size_t)d * 16], s);
        sc[lane] = s;
    }
    __syncthreads();
    if (lane == 0) {
        float bv = -1e30f, sv = -1e30f; int bi = 0, si = 0;
#pragma unroll
        for (int e = 0; e < 16; ++e) {
            float v = sc[e];
            if (v > bv) { sv = bv; si = bi; bv = v; bi = e; }
            else if (v > sv) { sv = v; si = e; }
        }
        size_t base = (size_t)g * 128 + (size_t)bcol * 2;
        out[base]            = bv;
        out[base + 1]        = sv;
        out[4096 + base]     = sc[16 + bi];
        out[4096 + base + 1] = sc[16 + si];
    }
}

// ---------------------------------------------------------------------------
static void run_layer(float* X, float* XN, float* BIG, float* Qb, float* Kb, float* Vb,
                      float* AO, float* MID,
                      const float* qkv_w, const float* o_w,
                      const float* up_w, const float* down_w,
                      const float* n1, const float* n2,
                      const int* doc, int G, int Sg, hipStream_t stream) {
    int T = G * Sg;
    rmsnorm_kernel<<<T, 256, 0, stream>>>(X, n1, XN);
    gemm_kernel<<<dim3(1536 / 64, T / 64), 256, 0, stream>>>(XN, qkv_w, nullptr, BIG, T, 1536, 512);
    int rp = T * 256;
    rope_pack_kernel<<<(rp + 255) / 256, 256, 0, stream>>>(BIG, Qb, Kb, Vb, Sg, rp);
    if (doc)
        attn_kernel<true, false><<<G * 8 * Sg, 64, 0, stream>>>(Qb, Kb, Vb, doc, AO, Sg);
    else
        attn_kernel<false, true><<<G * 8 * Sg, 64, 0, stream>>>(Qb, Kb, Vb, nullptr, AO, Sg);
    gemm_kernel<<<dim3(512 / 64, T / 64), 256, 0, stream>>>(AO, o_w, X, X, T, 512, 512);
    rmsnorm_kernel<<<T, 256, 0, stream>>>(X, n2, XN);
    gemm_kernel<<<dim3(2048 / 64, T / 64), 256, 0, stream>>>(XN, up_w, nullptr, BIG, T, 2048, 512);
    silu_mul_kernel<<<(T * 1024 + 255) / 256, 256, 0, stream>>>(BIG, MID, T * 1024);
    gemm_kernel<<<dim3(512 / 64, T / 64), 256, 0, stream>>>(MID, down_w, X, X, T, 512, 1024);
}

extern "C" void kernel_launch(void* const* d_in, const int* in_sizes, int n_in,
                              void* d_out, int out_size, void* d_ws, size_t ws_size,
                              hipStream_t stream) {
    const float* x_in    = (const float*)d_in[0];
    const int*   doc     = (const int*)d_in[1];
    const float* rt      = (const float*)d_in[2];
    const float* out_w   = (const float*)d_in[3];
    const float* k_rt    = (const float*)d_in[4];
    const float* k_gt    = (const float*)d_in[5];
    const float* enc_qkv = (const float*)d_in[6];
    const float* enc_o   = (const float*)d_in[7];
    const float* enc_up  = (const float*)d_in[8];
    const float* enc_dn  = (const float*)d_in[9];
    const float* enc_n1  = (const float*)d_in[10];
    const float* enc_n2  = (const float*)d_in[11];
    const float* rtr_qkv = (const float*)d_in[12];
    const float* rtr_o   = (const float*)d_in[13];
    const float* rtr_up  = (const float*)d_in[14];
    const float* rtr_dn  = (const float*)d_in[15];
    const float* rtr_n1  = (const float*)d_in[16];
    const float* rtr_n2  = (const float*)d_in[17];

    float* ws = (float*)d_ws;
    size_t off = 0;
    auto alloc = [&](size_t n) { float* p = ws + off; off += n; return p; };
    float* X    = alloc(4608UL * 512);
    float* X2   = alloc(4608UL * 512);
    float* XN   = alloc(4608UL * 512);
    float* BIG  = alloc(4608UL * 2048);
    float* Qb   = alloc(4608UL * 512);
    float* Kb   = alloc(4608UL * 512);
    float* Vb   = alloc(4608UL * 512);
    float* RR   = alloc(512UL * 512);
    float* OUTM = alloc(512UL * 256);
    float* OUTN = alloc(512UL * 256);
    float* KRN  = alloc(32UL * 2048);
    float* KGN  = alloc(32UL * 2048);
    // dead-range aliases: AO reuses BIG (free after rope_pack, until up-proj);
    // MID reuses Qb..Kb (free after attention).
    float* AO  = BIG;
    float* MID = Qb;
    (void)ws_size; (void)in_sizes; (void)n_in; (void)out_size;

    // encoder stream: x (2,2048,512) -> mutable X
    copy_in_kernel<<<(2097152 + 255) / 256, 256, 0, stream>>>(x_in, X, 2097152);

    for (int i = 0; i < 4; ++i) {
        run_layer(X, XN, BIG, Qb, Kb, Vb, AO, MID,
                  enc_qkv + (size_t)i * 512 * 1536,
                  enc_o   + (size_t)i * 512 * 512,
                  enc_up  + (size_t)i * 512 * 2048,
                  enc_dn  + (size_t)i * 1024 * 512,
                  enc_n1 + (size_t)i * 512, enc_n2 + (size_t)i * 512,
                  doc, 2, 2048, stream);
    }

    // router stream: (64, 72, 512) = 64-token blocks + 8 broadcast router tokens
    int rb_total = 64 * 72 * 512;
    router_build_kernel<<<(rb_total + 255) / 256, 256, 0, stream>>>(X, rt, X2, rb_total);

    for (int i = 0; i < 2; ++i) {
        run_layer(X2, XN, BIG, Qb, Kb, Vb, AO, MID,
                  rtr_qkv + (size_t)i * 512 * 1536,
                  rtr_o   + (size_t)i * 512 * 512,
                  rtr_up  + (size_t)i * 512 * 2048,
                  rtr_dn  + (size_t)i * 1024 * 512,
                  rtr_n1 + (size_t)i * 512, rtr_n2 + (size_t)i * 512,
                  nullptr, 64, 72, stream);
    }

    // out = xr[:,64:] @ out_w  -> (512, 256)
    gather_rows_kernel<<<(512 * 512) / 256, 256, 0, stream>>>(X2, RR, 512 * 512);
    gemm_kernel<<<dim3(256 / 64, 512 / 64), 256, 0, stream>>>(RR, out_w, nullptr, OUTM, 512, 256, 512);

    // l2 norms (commute with the expand permutation), logits, top-2
    norm_half_kernel<<<1024, 64, 0, stream>>>(OUTM, OUTN);
    norm_keys_kernel<<<512, 64, 0, stream>>>(k_rt, KRN);
    norm_keys_kernel<<<512, 64, 0, stream>>>(k_gt, KGN);
    logits_top2_kernel<<<2048, 64, 0, stream>>>(OUTN, KRN, KGN, (float*)d_out);
}

// Round 6
// 2831.100 us; speedup vs baseline: 2.0976x; 2.0976x over previous
//
#include <hip/hip_runtime.h>
#include <hip/hip_bf16.h>
#include <cstdint>

// ---------------------------------------------------------------------------
// B=2 S=2048 D=512 H=8 HD=64, FFH=1024. Encoder: 4 layers, G=2, Sg=2048
// (block-causal-64 AND doc mask). Router: 2 layers, G=64, Sg=72, full attn.
// Round 6: fix the real NaN root cause of rounds 3-5 — MID (T x 1024) was
// aliased onto Vb (T x 512); silu overflowed 9MB into the weight buffer.
// MID now spans Qb+Kb (adjacent, dead after attention) = exactly T x 1024.
// ---------------------------------------------------------------------------

typedef __attribute__((ext_vector_type(8))) short short8;   // 8 bf16 = 4 VGPR
typedef __attribute__((ext_vector_type(4))) float f32x4;

__device__ __forceinline__ float bf2f(unsigned short u) {
    return __uint_as_float(((unsigned)u) << 16);
}
__device__ __forceinline__ unsigned short f2bf(float f) {
    unsigned u = __float_as_uint(f);
    unsigned r = 0x7FFFu + ((u >> 16) & 1u);
    return (unsigned short)((u + r) >> 16);
}
__device__ __forceinline__ float wave_sum64(float v) {
#pragma unroll
    for (int o = 32; o; o >>= 1) v += __shfl_xor(v, o);
    return v;
}

#define MFMA16(a, b, c) __builtin_amdgcn_mfma_f32_16x16x32_bf16(a, b, c, 0, 0, 0)

// ---- f32 copy (input x -> mutable X) --------------------------------------
__global__ void copy_in_kernel(const float* __restrict__ src,
                               float* __restrict__ dst, int n) {
    int i = blockIdx.x * 256 + threadIdx.x;
    if (i < n) dst[i] = src[i];
}

// ---- weight transpose + hi/lo bf16 split: W[K,N] -> WT_hi/lo[N,K] ---------
__global__ __launch_bounds__(256) void wsplit_kernel(const float* __restrict__ W,
        unsigned short* __restrict__ WH, unsigned short* __restrict__ WL,
        int K, int N) {
    __shared__ float tile[32][33];
    int bn = blockIdx.x * 32, bk = blockIdx.y * 32;
    int tx = threadIdx.x & 31, ty = threadIdx.x >> 5;
#pragma unroll
    for (int i = 0; i < 4; ++i)
        tile[ty + 8 * i][tx] = W[(size_t)(bk + ty + 8 * i) * N + bn + tx];
    __syncthreads();
#pragma unroll
    for (int i = 0; i < 4; ++i) {
        int n = bn + ty + 8 * i, k = bk + tx;
        float x = tile[tx][ty + 8 * i];
        unsigned short h = f2bf(x);
        unsigned short lo = f2bf(x - bf2f(h));
        WH[(size_t)n * K + k] = h;
        WL[(size_t)n * K + k] = lo;
    }
}

// ---- RMSNorm over D=512 ---------------------------------------------------
__global__ __launch_bounds__(256) void rmsnorm_kernel(const float* __restrict__ X,
        const float* __restrict__ W, float* __restrict__ XN) {
    int t = blockIdx.x, tid = threadIdx.x;
    const float* xr = X + (size_t)t * 512;
    float v0 = xr[tid], v1 = xr[tid + 256];
    float ss = wave_sum64(v0 * v0 + v1 * v1);
    __shared__ float red[4];
    if ((tid & 63) == 0) red[tid >> 6] = ss;
    __syncthreads();
    float tot = red[0] + red[1] + red[2] + red[3];
    float scale = rsqrtf(tot * (1.0f / 512.0f) + 1e-6f);
    float* xo = XN + (size_t)t * 512;
    xo[tid]       = v0 * scale * W[tid];
    xo[tid + 256] = v1 * scale * W[tid + 256];
}

// ---- bf16x3 MFMA GEMM: C[M,N] = A[M,K](f32) @ B (pre-split WT[N,K]) + Res -
// 128x128 tile, BK=32, 256 thr = 4 waves, each wave 64x64 = 4x4 mfma tiles.
__global__ __launch_bounds__(256) void gemm_mfma(const float* __restrict__ A,
        const unsigned short* __restrict__ BH, const unsigned short* __restrict__ BL,
        const float* __restrict__ Res, float* __restrict__ C, int M, int N, int K) {
    __shared__ __align__(16) unsigned short Ah[128][40];  // pad 32->40: 2-way banks
    __shared__ __align__(16) unsigned short Al[128][40];
    __shared__ __align__(16) unsigned short Bh[128][40];
    __shared__ __align__(16) unsigned short Bl[128][40];
    int tid = threadIdx.x;
    int n0 = blockIdx.x * 128, m0 = blockIdx.y * 128;
    int wid = tid >> 6, lane = tid & 63;
    int wm = (wid >> 1) * 64, wn = (wid & 1) * 64;
    int col = lane & 15, quad = lane >> 4;
    int sr = tid >> 1, sc = (tid & 1) * 16;
    const float* Ag = A + (size_t)(m0 + sr) * K + sc;
    const unsigned short* BHg = BH + (size_t)(n0 + sr) * K + sc;
    const unsigned short* BLg = BL + (size_t)(n0 + sr) * K + sc;

    f32x4 acc[4][4] = {};
    float4 ar[4];
    uint4 bhr[2], blr[2];
#pragma unroll
    for (int t = 0; t < 4; ++t) ar[t] = *(const float4*)(Ag + 4 * t);
    bhr[0] = *(const uint4*)BHg;  bhr[1] = *(const uint4*)(BHg + 8);
    blr[0] = *(const uint4*)BLg;  blr[1] = *(const uint4*)(BLg + 8);

    int nk = K >> 5;
#pragma unroll 1
    for (int kc = 0; kc < nk; ++kc) {
        if (kc) __syncthreads();
#pragma unroll
        for (int t = 0; t < 4; ++t) {
            float4 v = ar[t];
            ushort4 h, l;
            h.x = f2bf(v.x); l.x = f2bf(v.x - bf2f(h.x));
            h.y = f2bf(v.y); l.y = f2bf(v.y - bf2f(h.y));
            h.z = f2bf(v.z); l.z = f2bf(v.z - bf2f(h.z));
            h.w = f2bf(v.w); l.w = f2bf(v.w - bf2f(h.w));
            *(ushort4*)&Ah[sr][sc + 4 * t] = h;
            *(ushort4*)&Al[sr][sc + 4 * t] = l;
        }
        *(uint4*)&Bh[sr][sc]     = bhr[0];
        *(uint4*)&Bh[sr][sc + 8] = bhr[1];
        *(uint4*)&Bl[sr][sc]     = blr[0];
        *(uint4*)&Bl[sr][sc + 8] = blr[1];
        __syncthreads();
        if (kc + 1 < nk) {  // prefetch next chunk (overlaps MFMA below)
            int k0 = (kc + 1) * 32;
#pragma unroll
            for (int t = 0; t < 4; ++t) ar[t] = *(const float4*)(Ag + k0 + 4 * t);
            bhr[0] = *(const uint4*)(BHg + k0);  bhr[1] = *(const uint4*)(BHg + k0 + 8);
            blr[0] = *(const uint4*)(BLg + k0);  blr[1] = *(const uint4*)(BLg + k0 + 8);
        }
        short8 afh[4], afl[4], bfh[4], bfl[4];
#pragma unroll
        for (int i = 0; i < 4; ++i) {
            afh[i] = *(const short8*)&Ah[wm + i * 16 + col][quad * 8];
            afl[i] = *(const short8*)&Al[wm + i * 16 + col][quad * 8];
            bfh[i] = *(const short8*)&Bh[wn + i * 16 + col][quad * 8];
            bfl[i] = *(const short8*)&Bl[wn + i * 16 + col][quad * 8];
        }
#pragma unroll
        for (int mi = 0; mi < 4; ++mi)
#pragma unroll
            for (int ni = 0; ni < 4; ++ni) {
                f32x4 c = acc[mi][ni];
                c = MFMA16(afh[mi], bfh[ni], c);
                c = MFMA16(afh[mi], bfl[ni], c);
                c = MFMA16(afl[mi], bfh[ni], c);
                acc[mi][ni] = c;
            }
    }
    // epilogue: C/D layout col=lane&15, row=quad*4+reg (verified mapping)
#pragma unroll
    for (int mi = 0; mi < 4; ++mi)
#pragma unroll
        for (int ni = 0; ni < 4; ++ni)
#pragma unroll
            for (int r = 0; r < 4; ++r) {
                int row = m0 + wm + mi * 16 + quad * 4 + r;
                int ccol = n0 + wn + ni * 16 + col;
                size_t o = (size_t)row * N + ccol;
                float v = acc[mi][ni][r];
                if (Res) v += Res[o];
                C[o] = v;
            }
}

// ---- split qkv + RoPE + transpose to (g,h,s,hd) ---------------------------
__global__ void rope_pack_kernel(const float* __restrict__ QKV, float* __restrict__ Q,
        float* __restrict__ K, float* __restrict__ V, int Sg, int total) {
    int idx = blockIdx.x * 256 + threadIdx.x;
    if (idx >= total) return;
    int i = idx & 31;
    int h = (idx >> 5) & 7;
    int t = idx >> 8;
    int g = t / Sg; int s = t - g * Sg;
    const float* row = QKV + (size_t)t * 1536;
    float inv = powf(10000.0f, -(float)(2 * i) / 64.0f);
    float sn, cs;
    sincosf((float)s * inv, &sn, &cs);
    size_t ob = ((size_t)(g * 8 + h) * Sg + s) * 64 + i;
    int c = h * 64 + i;
    float q1 = row[c], q2 = row[c + 32];
    Q[ob]      = q1 * cs + q2 * sn;
    Q[ob + 32] = q2 * cs - q1 * sn;
    float k1 = row[512 + c], k2 = row[512 + c + 32];
    K[ob]      = k1 * cs + k2 * sn;
    K[ob + 32] = k2 * cs - k1 * sn;
    V[ob]      = row[1024 + c];
    V[ob + 32] = row[1024 + c + 32];
}

// ---- tiled flash attention: workgroup per (qb64, gh); 4 waves x 16 q-rows -
// lane = (qi=lane>>2, dg=lane&3): each lane owns a 16-dim d-slice of one q.
template <bool MASKED>
__global__ __launch_bounds__(256) void attn2_kernel(const float* __restrict__ Q,
        const float* __restrict__ K, const float* __restrict__ V,
        const int* __restrict__ doc, float* __restrict__ AO, int Sg) {
    __shared__ __align__(16) float Ks[64][68];
    __shared__ __align__(16) float Vs[64][68];
    __shared__ int docs[64];
    int qb = (int)(gridDim.x - 1 - blockIdx.x);  // big qb first (load balance)
    int gh = blockIdx.y, g = gh >> 3;
    int tid = threadIdx.x, wid = tid >> 6, lane = tid & 63;
    int qi = lane >> 2, dg = lane & 3;
    int q = qb * 64 + wid * 16 + qi;
    bool qvalid = q < Sg;
    int qc = qvalid ? q : (Sg - 1);
    float qr[16];
    {
        const float* Qp = Q + ((size_t)gh * Sg + qc) * 64 + dg * 16;
#pragma unroll
        for (int t = 0; t < 4; ++t) {
            float4 v = *(const float4*)(Qp + 4 * t);
            qr[4 * t] = v.x; qr[4 * t + 1] = v.y;
            qr[4 * t + 2] = v.z; qr[4 * t + 3] = v.w;
        }
    }
    int mydoc = 0, wqd0 = 0, wqd1 = 0;
    if (MASKED) {
        mydoc = doc[(size_t)g * Sg + qc];
        int qa = qb * 64 + wid * 16, qz = qa + 15;
        if (qa >= Sg) qa = Sg - 1;
        if (qz >= Sg) qz = Sg - 1;
        wqd0 = doc[(size_t)g * Sg + qa];  // doc sorted -> wave doc range
        wqd1 = doc[(size_t)g * Sg + qz];
    }
    float m = -1e30f, l = 0.f, o[16];
#pragma unroll
    for (int t = 0; t < 16; ++t) o[t] = 0.f;
    int kblocks = MASKED ? (qb + 1) : ((Sg + 63) >> 6);
    int srr = tid >> 2, scc = (tid & 3) * 16;
    for (int kk = 0; kk < kblocks; ++kk) {
        int kvalid = Sg - kk * 64; if (kvalid > 64) kvalid = 64;
        __syncthreads();
        if (srr < kvalid) {
            const float* Kg = K + ((size_t)gh * Sg + kk * 64 + srr) * 64 + scc;
            const float* Vg = V + ((size_t)gh * Sg + kk * 64 + srr) * 64 + scc;
#pragma unroll
            for (int t = 0; t < 4; ++t) {
                *(float4*)&Ks[srr][scc + 4 * t] = *(const float4*)(Kg + 4 * t);
                *(float4*)&Vs[srr][scc + 4 * t] = *(const float4*)(Vg + 4 * t);
            }
        }
        if (MASKED && tid < 64)
            docs[tid] = (tid < kvalid) ? doc[(size_t)g * Sg + kk * 64 + tid] : -1;
        __syncthreads();
        bool skip = false;
        if (MASKED) {
            int kd0 = docs[0], kd1 = docs[kvalid - 1];
            skip = (kd1 < wqd0) || (kd0 > wqd1);  // sorted docs: no overlap
        }
        if (!skip) {
            for (int j = 0; j < kvalid; ++j) {
                float s = 0.f;
#pragma unroll
                for (int t = 0; t < 4; ++t) {
                    float4 kv = *(const float4*)&Ks[j][dg * 16 + 4 * t];
                    s = fmaf(qr[4 * t], kv.x, s);
                    s = fmaf(qr[4 * t + 1], kv.y, s);
                    s = fmaf(qr[4 * t + 2], kv.z, s);
                    s = fmaf(qr[4 * t + 3], kv.w, s);
                }
                s += __shfl_xor(s, 1);
                s += __shfl_xor(s, 2);   // sum over dg (4 lanes)
                s *= 0.125f;
                bool pred = qvalid;
                if (MASKED) pred = pred && (docs[j] == mydoc);
                float sv = pred ? s : -1e30f;
                float mn = fmaxf(m, sv);
                float scale = __expf(m - mn);
                float p = pred ? __expf(sv - mn) : 0.f;
                l = l * scale + p;
                m = mn;
#pragma unroll
                for (int t = 0; t < 4; ++t) {
                    float4 vv = *(const float4*)&Vs[j][dg * 16 + 4 * t];
                    o[4 * t]     = o[4 * t]     * scale + p * vv.x;
                    o[4 * t + 1] = o[4 * t + 1] * scale + p * vv.y;
                    o[4 * t + 2] = o[4 * t + 2] * scale + p * vv.z;
                    o[4 * t + 3] = o[4 * t + 3] * scale + p * vv.w;
                }
            }
        }
    }
    if (qvalid) {
        float inv = 1.0f / l;
        float* dst = AO + ((size_t)g * Sg + q) * 512 + (gh & 7) * 64 + dg * 16;
#pragma unroll
        for (int t = 0; t < 4; ++t) {
            float4 v = make_float4(o[4 * t] * inv, o[4 * t + 1] * inv,
                                   o[4 * t + 2] * inv, o[4 * t + 3] * inv);
            *(float4*)(dst + 4 * t) = v;
        }
    }
}

// ---- silu(h1)*h2 ----------------------------------------------------------
__global__ void silu_mul_kernel(const float* __restrict__ H, float* __restrict__ Mid, int total) {
    int idx = blockIdx.x * 256 + threadIdx.x;
    if (idx >= total) return;
    int t = idx >> 10, j = idx & 1023;
    float a = H[(size_t)t * 2048 + j];
    float b = H[(size_t)t * 2048 + 1024 + j];
    Mid[idx] = (a / (1.0f + __expf(-a))) * b;
}

// ---- build router stream: (64 groups) x (64 tokens + 8 router tokens) -----
__global__ void router_build_kernel(const float* __restrict__ X,
        const float* __restrict__ RT, float* __restrict__ X2, int total) {
    int idx = blockIdx.x * 256 + threadIdx.x;
    if (idx >= total) return;
    int d = idx & 511;
    int p = (idx >> 9) % 72;
    int g2 = idx / (72 * 512);
    X2[idx] = (p < 64) ? X[((size_t)g2 * 64 + p) * 512 + d]
                       : RT[(p - 64) * 512 + d];
}

// ---- gather xr[:,64:72,:] into dense (512,512) ----------------------------
__global__ void gather_rows_kernel(const float* __restrict__ X2, float* __restrict__ RR, int total) {
    int idx = blockIdx.x * 256 + threadIdx.x;
    if (idx >= total) return;
    int d = idx & 511;
    int row = idx >> 9;
    int g2 = row >> 3, rr = row & 7;
    RR[idx] = X2[((size_t)(g2 * 72 + 64 + rr)) * 512 + d];
}

// ---- l2-normalize each 128-half of each out row (l2n commutes w/ expand) --
__global__ __launch_bounds__(64) void norm_half_kernel(const float* __restrict__ IN,
        float* __restrict__ OUT) {
    int b = blockIdx.x; int lane = threadIdx.x;
    size_t base = (size_t)(b >> 1) * 256 + (size_t)(b & 1) * 128;
    float v0 = IN[base + lane], v1 = IN[base + 64 + lane];
    float ss = wave_sum64(v0 * v0 + v1 * v1);
    float sc = 1.0f / fmaxf(sqrtf(ss), 1e-12f);
    OUT[base + lane]      = v0 * sc;
    OUT[base + 64 + lane] = v1 * sc;
}

// ---- l2-normalize key columns: keys (32,128,16) over d --------------------
__global__ __launch_bounds__(64) void norm_keys_kernel(const float* __restrict__ Kin,
        float* __restrict__ Kout) {
    int b = blockIdx.x; int lane = threadIdx.x;
    int g = b >> 4, e = b & 15;
    size_t base = (size_t)g * 2048 + e;
    float v0 = Kin[base + (size_t)lane * 16];
    float v1 = Kin[base + (size_t)(lane + 64) * 16];
    float ss = wave_sum64(v0 * v0 + v1 * v1);
    float sc = 1.0f / fmaxf(sqrtf(ss), 1e-12f);
    Kout[base + (size_t)lane * 16]        = v0 * sc;
    Kout[base + (size_t)(lane + 64) * 16] = v1 * sc;
}

// ---- logits + top2 (stable, jax tie-break) --------------------------------
__global__ __launch_bounds__(64) void logits_top2_kernel(const float* __restrict__ OUTN,
        const float* __restrict__ KRN, const float* __restrict__ KGN,
        float* __restrict__ out) {
    int blk = blockIdx.x;
    int g = blk >> 6, bcol = blk & 63;
    int b = bcol >> 5, l = bcol & 31;
    int lsrc = (l + 31) & 31;     // roll(+1): element l comes from l-1
    int r = g >> 2;               // repeat RM=4
    int row = (b * 32 + lsrc) * 8 + r;
    const float* rvec = OUTN + (size_t)row * 256;
    __shared__ float sc[32];
    int lane = threadIdx.x;
    if (lane < 32) {
        int e = lane & 15;
        const float* kb = ((lane < 16) ? KRN : KGN) + (size_t)g * 2048 + e;
        const float* xv = (lane < 16) ? rvec : (rvec + 128);
        float s = 0.f;
#pragma unroll 8
        for (int d = 0; d < 128; ++d) s = fmaf(xv[d], kb[(size_t)d * 16], s);
        sc[lane] = s;
    }
    __syncthreads();
    if (lane == 0) {
        float bv = -1e30f, sv = -1e30f; int bi = 0, si = 0;
#pragma unroll
        for (int e = 0; e < 16; ++e) {
            float v = sc[e];
            if (v > bv) { sv = bv; si = bi; bv = v; bi = e; }
            else if (v > sv) { sv = v; si = e; }
        }
        size_t base = (size_t)g * 128 + (size_t)bcol * 2;
        out[base]            = bv;
        out[base + 1]        = sv;
        out[4096 + base]     = sc[16 + bi];
        out[4096 + base + 1] = sc[16 + si];
    }
}

// ---------------------------------------------------------------------------
static void run_layer(float* X, float* XN, float* BIG, float* Qb, float* Kb, float* Vb,
                      float* AO, float* MID,
                      const unsigned short* WH, const unsigned short* WL,
                      const float* n1, const float* n2,
                      const int* doc, int G, int Sg, hipStream_t stream) {
    // per-layer weight slots within WH/WL (ushort offsets)
    const size_t oQKV = 0, oO = 786432, oUP = 1048576, oDN = 2097152;
    int T = G * Sg;
    rmsnorm_kernel<<<T, 256, 0, stream>>>(X, n1, XN);
    gemm_mfma<<<dim3(1536 / 128, T / 128), 256, 0, stream>>>(XN, WH + oQKV, WL + oQKV, nullptr, BIG, T, 1536, 512);
    int rp = T * 256;
    rope_pack_kernel<<<(rp + 255) / 256, 256, 0, stream>>>(BIG, Qb, Kb, Vb, Sg, rp);
    int qblocks = (Sg + 63) >> 6;
    if (doc)
        attn2_kernel<true><<<dim3(qblocks, G * 8), 256, 0, stream>>>(Qb, Kb, Vb, doc, AO, Sg);
    else
        attn2_kernel<false><<<dim3(qblocks, G * 8), 256, 0, stream>>>(Qb, Kb, Vb, nullptr, AO, Sg);
    gemm_mfma<<<dim3(512 / 128, T / 128), 256, 0, stream>>>(AO, WH + oO, WL + oO, X, X, T, 512, 512);
    rmsnorm_kernel<<<T, 256, 0, stream>>>(X, n2, XN);
    gemm_mfma<<<dim3(2048 / 128, T / 128), 256, 0, stream>>>(XN, WH + oUP, WL + oUP, nullptr, BIG, T, 2048, 512);
    silu_mul_kernel<<<(T * 1024 + 255) / 256, 256, 0, stream>>>(BIG, MID, T * 1024);
    gemm_mfma<<<dim3(512 / 128, T / 128), 256, 0, stream>>>(MID, WH + oDN, WL + oDN, X, X, T, 512, 1024);
}

static void split_layer(const float* qkv, const float* o, const float* up, const float* dn,
                        unsigned short* WH, unsigned short* WL, hipStream_t stream) {
    const size_t oQKV = 0, oO = 786432, oUP = 1048576, oDN = 2097152;
    wsplit_kernel<<<dim3(48, 16), 256, 0, stream>>>(qkv, WH + oQKV, WL + oQKV, 512, 1536);
    wsplit_kernel<<<dim3(16, 16), 256, 0, stream>>>(o,   WH + oO,   WL + oO,   512, 512);
    wsplit_kernel<<<dim3(64, 16), 256, 0, stream>>>(up,  WH + oUP,  WL + oUP,  512, 2048);
    wsplit_kernel<<<dim3(16, 32), 256, 0, stream>>>(dn,  WH + oDN,  WL + oDN,  1024, 512);
}

extern "C" void kernel_launch(void* const* d_in, const int* in_sizes, int n_in,
                              void* d_out, int out_size, void* d_ws, size_t ws_size,
                              hipStream_t stream) {
    const float* x_in    = (const float*)d_in[0];
    const int*   doc     = (const int*)d_in[1];
    const float* rt      = (const float*)d_in[2];
    const float* out_w   = (const float*)d_in[3];
    const float* k_rt    = (const float*)d_in[4];
    const float* k_gt    = (const float*)d_in[5];
    const float* enc_qkv = (const float*)d_in[6];
    const float* enc_o   = (const float*)d_in[7];
    const float* enc_up  = (const float*)d_in[8];
    const float* enc_dn  = (const float*)d_in[9];
    const float* enc_n1  = (const float*)d_in[10];
    const float* enc_n2  = (const float*)d_in[11];
    const float* rtr_qkv = (const float*)d_in[12];
    const float* rtr_o   = (const float*)d_in[13];
    const float* rtr_up  = (const float*)d_in[14];
    const float* rtr_dn  = (const float*)d_in[15];
    const float* rtr_n1  = (const float*)d_in[16];
    const float* rtr_n2  = (const float*)d_in[17];

    float* ws = (float*)d_ws;
    size_t off = 0;
    auto alloc = [&](size_t n) { float* p = ws + off; off += n; return p; };
    float* X    = alloc(4608UL * 512);
    float* X2   = alloc(4608UL * 512);
    float* BIG  = alloc(4608UL * 2048);
    float* Qb   = alloc(4608UL * 512);
    float* Kb   = alloc(4608UL * 512);
    float* Vb   = alloc(4608UL * 512);
    // per-layer split-weight buffer: 2,621,440 ushorts hi + 2,621,440 lo
    unsigned short* WH = (unsigned short*)(ws + off);
    unsigned short* WL = WH + 2621440UL;
    off += 2621440UL;  // 5,242,880 ushorts == 2,621,440 floats
    // total: 23,855,104 floats = 95.4 MB  (< 97.0 MB proven in round 2)
    // dead-range aliases (stream-ordered, non-overlapping lifetimes):
    float* XN  = Qb;   // XN live rms->gemm; Qb live rope->attn
    float* MID = Qb;   // MID is T x 1024 -> spans Qb AND Kb (both dead after
                       // attention; XN dead once up-gemm has read it).
                       // NOTE: rounds 3-5 aliased MID=Vb (T x 512) -> silu
                       // overflowed 9MB into the weight buffer -> NaN.
    float* AO  = BIG;  // AO live attn->o-gemm; BIG reused by up-gemm after
    // X is dead after router_build -> reuse for the tail buffers:
    float* RR   = X;             // 262,144
    float* OUTM = X + 262144;    // 131,072
    float* OUTN = X + 393216;    // 131,072
    float* KRN  = X + 524288;    //  65,536
    float* KGN  = X + 589824;    //  65,536  (end 655,360 < 2,359,296)
    (void)ws_size; (void)in_sizes; (void)n_in; (void)out_size;

    // encoder stream: x (2,2048,512) -> mutable X
    copy_in_kernel<<<(2097152 + 255) / 256, 256, 0, stream>>>(x_in, X, 2097152);

    for (int i = 0; i < 4; ++i) {
        split_layer(enc_qkv + (size_t)i * 512 * 1536,
                    enc_o   + (size_t)i * 512 * 512,
                    enc_up  + (size_t)i * 512 * 2048,
                    enc_dn  + (size_t)i * 1024 * 512, WH, WL, stream);
        run_layer(X, XN, BIG, Qb, Kb, Vb, AO, MID, WH, WL,
                  enc_n1 + (size_t)i * 512, enc_n2 + (size_t)i * 512,
                  doc, 2, 2048, stream);
    }

    // router stream: (64, 72, 512) = 64-token blocks + 8 broadcast router tokens
    int rb_total = 64 * 72 * 512;
    router_build_kernel<<<(rb_total + 255) / 256, 256, 0, stream>>>(X, rt, X2, rb_total);

    for (int i = 0; i < 2; ++i) {
        split_layer(rtr_qkv + (size_t)i * 512 * 1536,
                    rtr_o   + (size_t)i * 512 * 512,
                    rtr_up  + (size_t)i * 512 * 2048,
                    rtr_dn  + (size_t)i * 1024 * 512, WH, WL, stream);
        run_layer(X2, XN, BIG, Qb, Kb, Vb, AO, MID, WH, WL,
                  rtr_n1 + (size_t)i * 512, rtr_n2 + (size_t)i * 512,
                  nullptr, 64, 72, stream);
    }

    // out = xr[:,64:] @ out_w  -> (512, 256); RR=X (X dead after router_build)
    gather_rows_kernel<<<(512 * 512) / 256, 256, 0, stream>>>(X2, RR, 512 * 512);
    wsplit_kernel<<<dim3(8, 16), 256, 0, stream>>>(out_w, WH, WL, 512, 256);
    gemm_mfma<<<dim3(256 / 128, 512 / 128), 256, 0, stream>>>(RR, WH, WL, nullptr, OUTM, 512, 256, 512);

    // l2 norms (commute with the expand permutation), logits, top-2
    norm_half_kernel<<<1024, 64, 0, stream>>>(OUTM, OUTN);
    norm_keys_kernel<<<512, 64, 0, stream>>>(k_rt, KRN);
    norm_keys_kernel<<<512, 64, 0, stream>>>(k_gt, KGN);
    logits_top2_kernel<<<2048, 64, 0, stream>>>(OUTN, KRN, KGN, (float*)d_out);
}

// Round 7
// 2162.229 us; speedup vs baseline: 2.7465x; 1.3093x over previous
//
#include <hip/hip_runtime.h>
#include <hip/hip_bf16.h>
#include <cstdint>

// ---------------------------------------------------------------------------
// B=2 S=2048 D=512 H=8 HD=64, FFH=1024. Encoder: 4 layers, G=2, Sg=2048
// (block-causal-64 AND doc mask). Router: 2 layers, G=64, Sg=72, full attn.
// Round 7: replace fp32-vector flash attention (233us/layer, VALUBusy 28%,
// MfmaUtil 0) with bf16x3 MFMA flash attention (attn3). GEMM path unchanged.
// ---------------------------------------------------------------------------

typedef __attribute__((ext_vector_type(8))) short short8;   // 8 bf16 = 4 VGPR
typedef __attribute__((ext_vector_type(4))) float f32x4;

__device__ __forceinline__ float bf2f(unsigned short u) {
    return __uint_as_float(((unsigned)u) << 16);
}
__device__ __forceinline__ unsigned short f2bf(float f) {
    unsigned u = __float_as_uint(f);
    unsigned r = 0x7FFFu + ((u >> 16) & 1u);
    return (unsigned short)((u + r) >> 16);
}
__device__ __forceinline__ float wave_sum64(float v) {
#pragma unroll
    for (int o = 32; o; o >>= 1) v += __shfl_xor(v, o);
    return v;
}

#define MFMA16(a, b, c) __builtin_amdgcn_mfma_f32_16x16x32_bf16(a, b, c, 0, 0, 0)

// ---- f32 copy (input x -> mutable X) --------------------------------------
__global__ void copy_in_kernel(const float* __restrict__ src,
                               float* __restrict__ dst, int n) {
    int i = blockIdx.x * 256 + threadIdx.x;
    if (i < n) dst[i] = src[i];
}

// ---- weight transpose + hi/lo bf16 split: W[K,N] -> WT_hi/lo[N,K] ---------
__global__ __launch_bounds__(256) void wsplit_kernel(const float* __restrict__ W,
        unsigned short* __restrict__ WH, unsigned short* __restrict__ WL,
        int K, int N) {
    __shared__ float tile[32][33];
    int bn = blockIdx.x * 32, bk = blockIdx.y * 32;
    int tx = threadIdx.x & 31, ty = threadIdx.x >> 5;
#pragma unroll
    for (int i = 0; i < 4; ++i)
        tile[ty + 8 * i][tx] = W[(size_t)(bk + ty + 8 * i) * N + bn + tx];
    __syncthreads();
#pragma unroll
    for (int i = 0; i < 4; ++i) {
        int n = bn + ty + 8 * i, k = bk + tx;
        float x = tile[tx][ty + 8 * i];
        unsigned short h = f2bf(x);
        unsigned short lo = f2bf(x - bf2f(h));
        WH[(size_t)n * K + k] = h;
        WL[(size_t)n * K + k] = lo;
    }
}

// ---- RMSNorm over D=512 ---------------------------------------------------
__global__ __launch_bounds__(256) void rmsnorm_kernel(const float* __restrict__ X,
        const float* __restrict__ W, float* __restrict__ XN) {
    int t = blockIdx.x, tid = threadIdx.x;
    const float* xr = X + (size_t)t * 512;
    float v0 = xr[tid], v1 = xr[tid + 256];
    float ss = wave_sum64(v0 * v0 + v1 * v1);
    __shared__ float red[4];
    if ((tid & 63) == 0) red[tid >> 6] = ss;
    __syncthreads();
    float tot = red[0] + red[1] + red[2] + red[3];
    float scale = rsqrtf(tot * (1.0f / 512.0f) + 1e-6f);
    float* xo = XN + (size_t)t * 512;
    xo[tid]       = v0 * scale * W[tid];
    xo[tid + 256] = v1 * scale * W[tid + 256];
}

// ---- bf16x3 MFMA GEMM: C[M,N] = A[M,K](f32) @ B (pre-split WT[N,K]) + Res -
__global__ __launch_bounds__(256) void gemm_mfma(const float* __restrict__ A,
        const unsigned short* __restrict__ BH, const unsigned short* __restrict__ BL,
        const float* __restrict__ Res, float* __restrict__ C, int M, int N, int K) {
    __shared__ __align__(16) unsigned short Ah[128][40];
    __shared__ __align__(16) unsigned short Al[128][40];
    __shared__ __align__(16) unsigned short Bh[128][40];
    __shared__ __align__(16) unsigned short Bl[128][40];
    int tid = threadIdx.x;
    int n0 = blockIdx.x * 128, m0 = blockIdx.y * 128;
    int wid = tid >> 6, lane = tid & 63;
    int wm = (wid >> 1) * 64, wn = (wid & 1) * 64;
    int col = lane & 15, quad = lane >> 4;
    int sr = tid >> 1, sc = (tid & 1) * 16;
    const float* Ag = A + (size_t)(m0 + sr) * K + sc;
    const unsigned short* BHg = BH + (size_t)(n0 + sr) * K + sc;
    const unsigned short* BLg = BL + (size_t)(n0 + sr) * K + sc;

    f32x4 acc[4][4] = {};
    float4 ar[4];
    uint4 bhr[2], blr[2];
#pragma unroll
    for (int t = 0; t < 4; ++t) ar[t] = *(const float4*)(Ag + 4 * t);
    bhr[0] = *(const uint4*)BHg;  bhr[1] = *(const uint4*)(BHg + 8);
    blr[0] = *(const uint4*)BLg;  blr[1] = *(const uint4*)(BLg + 8);

    int nk = K >> 5;
#pragma unroll 1
    for (int kc = 0; kc < nk; ++kc) {
        if (kc) __syncthreads();
#pragma unroll
        for (int t = 0; t < 4; ++t) {
            float4 v = ar[t];
            ushort4 h, l;
            h.x = f2bf(v.x); l.x = f2bf(v.x - bf2f(h.x));
            h.y = f2bf(v.y); l.y = f2bf(v.y - bf2f(h.y));
            h.z = f2bf(v.z); l.z = f2bf(v.z - bf2f(h.z));
            h.w = f2bf(v.w); l.w = f2bf(v.w - bf2f(h.w));
            *(ushort4*)&Ah[sr][sc + 4 * t] = h;
            *(ushort4*)&Al[sr][sc + 4 * t] = l;
        }
        *(uint4*)&Bh[sr][sc]     = bhr[0];
        *(uint4*)&Bh[sr][sc + 8] = bhr[1];
        *(uint4*)&Bl[sr][sc]     = blr[0];
        *(uint4*)&Bl[sr][sc + 8] = blr[1];
        __syncthreads();
        if (kc + 1 < nk) {
            int k0 = (kc + 1) * 32;
#pragma unroll
            for (int t = 0; t < 4; ++t) ar[t] = *(const float4*)(Ag + k0 + 4 * t);
            bhr[0] = *(const uint4*)(BHg + k0);  bhr[1] = *(const uint4*)(BHg + k0 + 8);
            blr[0] = *(const uint4*)(BLg + k0);  blr[1] = *(const uint4*)(BLg + k0 + 8);
        }
        short8 afh[4], afl[4], bfh[4], bfl[4];
#pragma unroll
        for (int i = 0; i < 4; ++i) {
            afh[i] = *(const short8*)&Ah[wm + i * 16 + col][quad * 8];
            afl[i] = *(const short8*)&Al[wm + i * 16 + col][quad * 8];
            bfh[i] = *(const short8*)&Bh[wn + i * 16 + col][quad * 8];
            bfl[i] = *(const short8*)&Bl[wn + i * 16 + col][quad * 8];
        }
#pragma unroll
        for (int mi = 0; mi < 4; ++mi)
#pragma unroll
            for (int ni = 0; ni < 4; ++ni) {
                f32x4 c = acc[mi][ni];
                c = MFMA16(afh[mi], bfh[ni], c);
                c = MFMA16(afh[mi], bfl[ni], c);
                c = MFMA16(afl[mi], bfh[ni], c);
                acc[mi][ni] = c;
            }
    }
#pragma unroll
    for (int mi = 0; mi < 4; ++mi)
#pragma unroll
        for (int ni = 0; ni < 4; ++ni)
#pragma unroll
            for (int r = 0; r < 4; ++r) {
                int row = m0 + wm + mi * 16 + quad * 4 + r;
                int ccol = n0 + wn + ni * 16 + col;
                size_t o = (size_t)row * N + ccol;
                float v = acc[mi][ni][r];
                if (Res) v += Res[o];
                C[o] = v;
            }
}

// ---- split qkv + RoPE + transpose to (g,h,s,hd) ---------------------------
__global__ void rope_pack_kernel(const float* __restrict__ QKV, float* __restrict__ Q,
        float* __restrict__ K, float* __restrict__ V, int Sg, int total) {
    int idx = blockIdx.x * 256 + threadIdx.x;
    if (idx >= total) return;
    int i = idx & 31;
    int h = (idx >> 5) & 7;
    int t = idx >> 8;
    int g = t / Sg; int s = t - g * Sg;
    const float* row = QKV + (size_t)t * 1536;
    float inv = powf(10000.0f, -(float)(2 * i) / 64.0f);
    float sn, cs;
    sincosf((float)s * inv, &sn, &cs);
    size_t ob = ((size_t)(g * 8 + h) * Sg + s) * 64 + i;
    int c = h * 64 + i;
    float q1 = row[c], q2 = row[c + 32];
    Q[ob]      = q1 * cs + q2 * sn;
    Q[ob + 32] = q2 * cs - q1 * sn;
    float k1 = row[512 + c], k2 = row[512 + c + 32];
    K[ob]      = k1 * cs + k2 * sn;
    K[ob + 32] = k2 * cs - k1 * sn;
    V[ob]      = row[1024 + c];
    V[ob + 32] = row[1024 + c + 32];
}

// ---- MFMA flash attention (bf16x3 scores & PV) ----------------------------
// Block = (qb, gh): 64 q-rows; 4 waves x 16 q-rows. Per k-tile: K row-major,
// V transposed, hi/lo bf16 in LDS. Softmax in C-layout regs (row=quad*4+r).
// P round-trips through per-wave LDS slice (in-wave DS ordering, no barrier).
template <bool MASKED>
__global__ __launch_bounds__(256) void attn3_kernel(const float* __restrict__ Q,
        const float* __restrict__ K, const float* __restrict__ V,
        const int* __restrict__ doc, float* __restrict__ AO, int Sg) {
    __shared__ __align__(16) unsigned short Kh[64][72], Kl[64][72];
    __shared__ __align__(16) unsigned short Vth[64][72], Vtl[64][72];
    __shared__ __align__(16) unsigned short Ph[4][16][72], Pl[4][16][72];
    __shared__ int dock[64];
    int qb = (int)(gridDim.x - 1 - blockIdx.x);   // big qb first (load balance)
    int gh = blockIdx.y, g = gh >> 3;
    int tid = threadIdx.x, wid = tid >> 6, lane = tid & 63;
    int col = lane & 15, quad = lane >> 4;
    int srr = tid >> 2, scc = (tid & 3) * 16;

    // Q a-fragments straight from global (A-frag rows indexed by col), x0.125
    short8 qa[2][2];  // [kk][0=hi,1=lo]
    {
        int qrow = qb * 64 + wid * 16 + col;
        if (qrow >= Sg) qrow = Sg - 1;
        const float* Qg = Q + ((size_t)gh * Sg + qrow) * 64 + quad * 8;
#pragma unroll
        for (int kk = 0; kk < 2; ++kk) {
            float4 v0 = *(const float4*)(Qg + kk * 32);
            float4 v1 = *(const float4*)(Qg + kk * 32 + 4);
            float vv[8] = {v0.x, v0.y, v0.z, v0.w, v1.x, v1.y, v1.z, v1.w};
            short8 h, l;
#pragma unroll
            for (int e = 0; e < 8; ++e) {
                float x = vv[e] * 0.125f;
                unsigned short hb = f2bf(x);
                h[e] = (short)hb;
                l[e] = (short)f2bf(x - bf2f(hb));
            }
            qa[kk][0] = h; qa[kk][1] = l;
        }
    }
    int dqr[4]; int wq0 = 0, wq1 = 0, bq0 = 0, bq1 = 0;
    if (MASKED) {
        const int* db = doc + (size_t)g * Sg + qb * 64;
#pragma unroll
        for (int r = 0; r < 4; ++r) dqr[r] = db[wid * 16 + quad * 4 + r];
        wq0 = db[wid * 16]; wq1 = db[wid * 16 + 15];
        bq0 = db[0];        bq1 = db[63];
    }
    float m[4], l[4];
    f32x4 accO[4];
#pragma unroll
    for (int r = 0; r < 4; ++r) { m[r] = -1e30f; l[r] = 0.f; }
#pragma unroll
    for (int nd = 0; nd < 4; ++nd) accO[nd] = (f32x4){0.f, 0.f, 0.f, 0.f};

    int nkt = MASKED ? (qb + 1) : ((Sg + 63) >> 6);
    for (int kt = 0; kt < nkt; ++kt) {
        int kval = Sg - kt * 64; if (kval > 64) kval = 64;
        __syncthreads();                         // prior tile's LDS reads done
        if (MASKED && tid < 64) dock[tid] = doc[(size_t)g * Sg + kt * 64 + tid];
        __syncthreads();
        bool bskip = false;                      // uniform across block
        if (MASKED) bskip = (dock[63] < bq0) || (dock[0] > bq1);
        if (!bskip) {
            {   // stage K (row-major) and V^T, hi/lo split
                int krow = kt * 64 + srr;
                bool okr = krow < Sg;
                const float* Kg = K + ((size_t)gh * Sg + (okr ? krow : 0)) * 64 + scc;
                const float* Vg = V + ((size_t)gh * Sg + (okr ? krow : 0)) * 64 + scc;
#pragma unroll
                for (int t = 0; t < 4; ++t) {
                    float4 kv = okr ? *(const float4*)(Kg + 4 * t) : make_float4(0.f, 0.f, 0.f, 0.f);
                    float4 vv = okr ? *(const float4*)(Vg + 4 * t) : make_float4(0.f, 0.f, 0.f, 0.f);
                    float ka[4] = {kv.x, kv.y, kv.z, kv.w};
                    float va[4] = {vv.x, vv.y, vv.z, vv.w};
#pragma unroll
                    for (int e = 0; e < 4; ++e) {
                        int d = scc + 4 * t + e;
                        unsigned short h = f2bf(ka[e]);
                        Kh[srr][d] = h;
                        Kl[srr][d] = f2bf(ka[e] - bf2f(h));
                        unsigned short vh = f2bf(va[e]);
                        Vth[d][srr] = vh;
                        Vtl[d][srr] = f2bf(va[e] - bf2f(vh));
                    }
                }
            }
            __syncthreads();
            bool wskip = false;                  // uniform per wave only
            if (MASKED) wskip = (dock[kval - 1] < wq0) || (dock[0] > wq1);
            if (!wskip) {
                int dk[4];
                if (MASKED) {
#pragma unroll
                    for (int ni = 0; ni < 4; ++ni) dk[ni] = dock[ni * 16 + col];
                }
                // scores: 64x64 per block band, bf16x3
                f32x4 sc[4];
#pragma unroll
                for (int ni = 0; ni < 4; ++ni) {
                    f32x4 c = (f32x4){0.f, 0.f, 0.f, 0.f};
#pragma unroll
                    for (int kk = 0; kk < 2; ++kk) {
                        short8 bh = *(const short8*)&Kh[ni * 16 + col][kk * 32 + quad * 8];
                        short8 bl = *(const short8*)&Kl[ni * 16 + col][kk * 32 + quad * 8];
                        c = MFMA16(qa[kk][0], bh, c);
                        c = MFMA16(qa[kk][0], bl, c);
                        c = MFMA16(qa[kk][1], bh, c);
                    }
                    sc[ni] = c;
                }
                // mask + row max (rows live in quad-groups of 16 lanes)
                float mnew[4];
#pragma unroll
                for (int r = 0; r < 4; ++r) mnew[r] = -1e30f;
#pragma unroll
                for (int ni = 0; ni < 4; ++ni)
#pragma unroll
                    for (int r = 0; r < 4; ++r) {
                        bool ok = MASKED ? (dk[ni] == dqr[r]) : (ni * 16 + col < kval);
                        float s = ok ? sc[ni][r] : -1e30f;
                        sc[ni][r] = s;
                        mnew[r] = fmaxf(mnew[r], s);
                    }
#pragma unroll
                for (int r = 0; r < 4; ++r)
#pragma unroll
                    for (int o = 1; o < 16; o <<= 1)
                        mnew[r] = fmaxf(mnew[r], __shfl_xor(mnew[r], o));
                float alpha[4], lsum[4];
#pragma unroll
                for (int r = 0; r < 4; ++r) {
                    float M = fmaxf(m[r], mnew[r]);
                    alpha[r] = __expf(m[r] - M);
                    m[r] = M;
                    lsum[r] = 0.f;
                }
                // p = exp(s - M) (predicated!), split hi/lo into wave's P slice
#pragma unroll
                for (int ni = 0; ni < 4; ++ni)
#pragma unroll
                    for (int r = 0; r < 4; ++r) {
                        bool ok = MASKED ? (dk[ni] == dqr[r]) : (ni * 16 + col < kval);
                        float p = ok ? __expf(sc[ni][r] - m[r]) : 0.f;
                        lsum[r] += p;
                        unsigned short h = f2bf(p);
                        Ph[wid][quad * 4 + r][ni * 16 + col] = h;
                        Pl[wid][quad * 4 + r][ni * 16 + col] = f2bf(p - bf2f(h));
                    }
#pragma unroll
                for (int r = 0; r < 4; ++r) {
#pragma unroll
                    for (int o = 1; o < 16; o <<= 1)
                        lsum[r] += __shfl_xor(lsum[r], o);
                    l[r] = l[r] * alpha[r] + lsum[r];
                }
#pragma unroll
                for (int nd = 0; nd < 4; ++nd)
#pragma unroll
                    for (int r = 0; r < 4; ++r) accO[nd][r] *= alpha[r];
                // PV: O += P @ V (bf16x3); in-wave LDS RAW (DS ops are in-order)
#pragma unroll
                for (int kk = 0; kk < 2; ++kk) {
                    short8 pah = *(const short8*)&Ph[wid][col][kk * 32 + quad * 8];
                    short8 pal = *(const short8*)&Pl[wid][col][kk * 32 + quad * 8];
#pragma unroll
                    for (int nd = 0; nd < 4; ++nd) {
                        short8 vbh = *(const short8*)&Vth[nd * 16 + col][kk * 32 + quad * 8];
                        short8 vbl = *(const short8*)&Vtl[nd * 16 + col][kk * 32 + quad * 8];
                        f32x4 c = accO[nd];
                        c = MFMA16(pah, vbh, c);
                        c = MFMA16(pah, vbl, c);
                        c = MFMA16(pal, vbh, c);
                        accO[nd] = c;
                    }
                }
            }
        }
    }
#pragma unroll
    for (int r = 0; r < 4; ++r) {
        int qrow = qb * 64 + wid * 16 + quad * 4 + r;
        if (qrow < Sg) {
            float inv = 1.0f / l[r];
            float* dst = AO + ((size_t)g * Sg + qrow) * 512 + (gh & 7) * 64;
#pragma unroll
            for (int nd = 0; nd < 4; ++nd)
                dst[nd * 16 + col] = accO[nd][r] * inv;
        }
    }
}

// ---- silu(h1)*h2 ----------------------------------------------------------
__global__ void silu_mul_kernel(const float* __restrict__ H, float* __restrict__ Mid, int total) {
    int idx = blockIdx.x * 256 + threadIdx.x;
    if (idx >= total) return;
    int t = idx >> 10, j = idx & 1023;
    float a = H[(size_t)t * 2048 + j];
    float b = H[(size_t)t * 2048 + 1024 + j];
    Mid[idx] = (a / (1.0f + __expf(-a))) * b;
}

// ---- build router stream: (64 groups) x (64 tokens + 8 router tokens) -----
__global__ void router_build_kernel(const float* __restrict__ X,
        const float* __restrict__ RT, float* __restrict__ X2, int total) {
    int idx = blockIdx.x * 256 + threadIdx.x;
    if (idx >= total) return;
    int d = idx & 511;
    int p = (idx >> 9) % 72;
    int g2 = idx / (72 * 512);
    X2[idx] = (p < 64) ? X[((size_t)g2 * 64 + p) * 512 + d]
                       : RT[(p - 64) * 512 + d];
}

// ---- gather xr[:,64:72,:] into dense (512,512) ----------------------------
__global__ void gather_rows_kernel(const float* __restrict__ X2, float* __restrict__ RR, int total) {
    int idx = blockIdx.x * 256 + threadIdx.x;
    if (idx >= total) return;
    int d = idx & 511;
    int row = idx >> 9;
    int g2 = row >> 3, rr = row & 7;
    RR[idx] = X2[((size_t)(g2 * 72 + 64 + rr)) * 512 + d];
}

// ---- l2-normalize each 128-half of each out row (l2n commutes w/ expand) --
__global__ __launch_bounds__(64) void norm_half_kernel(const float* __restrict__ IN,
        float* __restrict__ OUT) {
    int b = blockIdx.x; int lane = threadIdx.x;
    size_t base = (size_t)(b >> 1) * 256 + (size_t)(b & 1) * 128;
    float v0 = IN[base + lane], v1 = IN[base + 64 + lane];
    float ss = wave_sum64(v0 * v0 + v1 * v1);
    float sc = 1.0f / fmaxf(sqrtf(ss), 1e-12f);
    OUT[base + lane]      = v0 * sc;
    OUT[base + 64 + lane] = v1 * sc;
}

// ---- l2-normalize key columns: keys (32,128,16) over d --------------------
__global__ __launch_bounds__(64) void norm_keys_kernel(const float* __restrict__ Kin,
        float* __restrict__ Kout) {
    int b = blockIdx.x; int lane = threadIdx.x;
    int g = b >> 4, e = b & 15;
    size_t base = (size_t)g * 2048 + e;
    float v0 = Kin[base + (size_t)lane * 16];
    float v1 = Kin[base + (size_t)(lane + 64) * 16];
    float ss = wave_sum64(v0 * v0 + v1 * v1);
    float sc = 1.0f / fmaxf(sqrtf(ss), 1e-12f);
    Kout[base + (size_t)lane * 16]        = v0 * sc;
    Kout[base + (size_t)(lane + 64) * 16] = v1 * sc;
}

// ---- logits + top2 (stable, jax tie-break) --------------------------------
__global__ __launch_bounds__(64) void logits_top2_kernel(const float* __restrict__ OUTN,
        const float* __restrict__ KRN, const float* __restrict__ KGN,
        float* __restrict__ out) {
    int blk = blockIdx.x;
    int g = blk >> 6, bcol = blk & 63;
    int b = bcol >> 5, l = bcol & 31;
    int lsrc = (l + 31) & 31;     // roll(+1): element l comes from l-1
    int r = g >> 2;               // repeat RM=4
    int row = (b * 32 + lsrc) * 8 + r;
    const float* rvec = OUTN + (size_t)row * 256;
    __shared__ float sc[32];
    int lane = threadIdx.x;
    if (lane < 32) {
        int e = lane & 15;
        const float* kb = ((lane < 16) ? KRN : KGN) + (size_t)g * 2048 + e;
        const float* xv = (lane < 16) ? rvec : (rvec + 128);
        float s = 0.f;
#pragma unroll 8
        for (int d = 0; d < 128; ++d) s = fmaf(xv[d], kb[(size_t)d * 16], s);
        sc[lane] = s;
    }
    __syncthreads();
    if (lane == 0) {
        float bv = -1e30f, sv = -1e30f; int bi = 0, si = 0;
#pragma unroll
        for (int e = 0; e < 16; ++e) {
            float v = sc[e];
            if (v > bv) { sv = bv; si = bi; bv = v; bi = e; }
            else if (v > sv) { sv = v; si = e; }
        }
        size_t base = (size_t)g * 128 + (size_t)bcol * 2;
        out[base]            = bv;
        out[base + 1]        = sv;
        out[4096 + base]     = sc[16 + bi];
        out[4096 + base + 1] = sc[16 + si];
    }
}

// ---------------------------------------------------------------------------
static void run_layer(float* X, float* XN, float* BIG, float* Qb, float* Kb, float* Vb,
                      float* AO, float* MID,
                      const unsigned short* WH, const unsigned short* WL,
                      const float* n1, const float* n2,
                      const int* doc, int G, int Sg, hipStream_t stream) {
    const size_t oQKV = 0, oO = 786432, oUP = 1048576, oDN = 2097152;
    int T = G * Sg;
    rmsnorm_kernel<<<T, 256, 0, stream>>>(X, n1, XN);
    gemm_mfma<<<dim3(1536 / 128, T / 128), 256, 0, stream>>>(XN, WH + oQKV, WL + oQKV, nullptr, BIG, T, 1536, 512);
    int rp = T * 256;
    rope_pack_kernel<<<(rp + 255) / 256, 256, 0, stream>>>(BIG, Qb, Kb, Vb, Sg, rp);
    int qblocks = (Sg + 63) >> 6;
    if (doc)
        attn3_kernel<true><<<dim3(qblocks, G * 8), 256, 0, stream>>>(Qb, Kb, Vb, doc, AO, Sg);
    else
        attn3_kernel<false><<<dim3(qblocks, G * 8), 256, 0, stream>>>(Qb, Kb, Vb, nullptr, AO, Sg);
    gemm_mfma<<<dim3(512 / 128, T / 128), 256, 0, stream>>>(AO, WH + oO, WL + oO, X, X, T, 512, 512);
    rmsnorm_kernel<<<T, 256, 0, stream>>>(X, n2, XN);
    gemm_mfma<<<dim3(2048 / 128, T / 128), 256, 0, stream>>>(XN, WH + oUP, WL + oUP, nullptr, BIG, T, 2048, 512);
    silu_mul_kernel<<<(T * 1024 + 255) / 256, 256, 0, stream>>>(BIG, MID, T * 1024);
    gemm_mfma<<<dim3(512 / 128, T / 128), 256, 0, stream>>>(MID, WH + oDN, WL + oDN, X, X, T, 512, 1024);
}

static void split_layer(const float* qkv, const float* o, const float* up, const float* dn,
                        unsigned short* WH, unsigned short* WL, hipStream_t stream) {
    const size_t oQKV = 0, oO = 786432, oUP = 1048576, oDN = 2097152;
    wsplit_kernel<<<dim3(48, 16), 256, 0, stream>>>(qkv, WH + oQKV, WL + oQKV, 512, 1536);
    wsplit_kernel<<<dim3(16, 16), 256, 0, stream>>>(o,   WH + oO,   WL + oO,   512, 512);
    wsplit_kernel<<<dim3(64, 16), 256, 0, stream>>>(up,  WH + oUP,  WL + oUP,  512, 2048);
    wsplit_kernel<<<dim3(16, 32), 256, 0, stream>>>(dn,  WH + oDN,  WL + oDN,  1024, 512);
}

extern "C" void kernel_launch(void* const* d_in, const int* in_sizes, int n_in,
                              void* d_out, int out_size, void* d_ws, size_t ws_size,
                              hipStream_t stream) {
    const float* x_in    = (const float*)d_in[0];
    const int*   doc     = (const int*)d_in[1];
    const float* rt      = (const float*)d_in[2];
    const float* out_w   = (const float*)d_in[3];
    const float* k_rt    = (const float*)d_in[4];
    const float* k_gt    = (const float*)d_in[5];
    const float* enc_qkv = (const float*)d_in[6];
    const float* enc_o   = (const float*)d_in[7];
    const float* enc_up  = (const float*)d_in[8];
    const float* enc_dn  = (const float*)d_in[9];
    const float* enc_n1  = (const float*)d_in[10];
    const float* enc_n2  = (const float*)d_in[11];
    const float* rtr_qkv = (const float*)d_in[12];
    const float* rtr_o   = (const float*)d_in[13];
    const float* rtr_up  = (const float*)d_in[14];
    const float* rtr_dn  = (const float*)d_in[15];
    const float* rtr_n1  = (const float*)d_in[16];
    const float* rtr_n2  = (const float*)d_in[17];

    float* ws = (float*)d_ws;
    size_t off = 0;
    auto alloc = [&](size_t n) { float* p = ws + off; off += n; return p; };
    float* X    = alloc(4608UL * 512);
    float* X2   = alloc(4608UL * 512);
    float* BIG  = alloc(4608UL * 2048);
    float* Qb   = alloc(4608UL * 512);
    float* Kb   = alloc(4608UL * 512);
    float* Vb   = alloc(4608UL * 512);
    unsigned short* WH = (unsigned short*)(ws + off);
    unsigned short* WL = WH + 2621440UL;
    off += 2621440UL;
    // dead-range aliases (stream-ordered, non-overlapping lifetimes):
    float* XN  = Qb;   // XN live rms->gemm; Qb live rope->attn
    float* MID = Qb;   // MID is T x 1024 -> spans Qb AND Kb (dead after attn)
    float* AO  = BIG;  // AO live attn->o-gemm; BIG reused by up-gemm after
    float* RR   = X;             // X dead after router_build
    float* OUTM = X + 262144;
    float* OUTN = X + 393216;
    float* KRN  = X + 524288;
    float* KGN  = X + 589824;
    (void)ws_size; (void)in_sizes; (void)n_in; (void)out_size;

    copy_in_kernel<<<(2097152 + 255) / 256, 256, 0, stream>>>(x_in, X, 2097152);

    for (int i = 0; i < 4; ++i) {
        split_layer(enc_qkv + (size_t)i * 512 * 1536,
                    enc_o   + (size_t)i * 512 * 512,
                    enc_up  + (size_t)i * 512 * 2048,
                    enc_dn  + (size_t)i * 1024 * 512, WH, WL, stream);
        run_layer(X, XN, BIG, Qb, Kb, Vb, AO, MID, WH, WL,
                  enc_n1 + (size_t)i * 512, enc_n2 + (size_t)i * 512,
                  doc, 2, 2048, stream);
    }

    int rb_total = 64 * 72 * 512;
    router_build_kernel<<<(rb_total + 255) / 256, 256, 0, stream>>>(X, rt, X2, rb_total);

    for (int i = 0; i < 2; ++i) {
        split_layer(rtr_qkv + (size_t)i * 512 * 1536,
                    rtr_o   + (size_t)i * 512 * 512,
                    rtr_up  + (size_t)i * 512 * 2048,
                    rtr_dn  + (size_t)i * 1024 * 512, WH, WL, stream);
        run_layer(X2, XN, BIG, Qb, Kb, Vb, AO, MID, WH, WL,
                  rtr_n1 + (size_t)i * 512, rtr_n2 + (size_t)i * 512,
                  nullptr, 64, 72, stream);
    }

    gather_rows_kernel<<<(512 * 512) / 256, 256, 0, stream>>>(X2, RR, 512 * 512);
    wsplit_kernel<<<dim3(8, 16), 256, 0, stream>>>(out_w, WH, WL, 512, 256);
    gemm_mfma<<<dim3(256 / 128, 512 / 128), 256, 0, stream>>>(RR, WH, WL, nullptr, OUTM, 512, 256, 512);

    norm_half_kernel<<<1024, 64, 0, stream>>>(OUTM, OUTN);
    norm_keys_kernel<<<512, 64, 0, stream>>>(k_rt, KRN);
    norm_keys_kernel<<<512, 64, 0, stream>>>(k_gt, KGN);
    logits_top2_kernel<<<2048, 64, 0, stream>>>(OUTN, KRN, KGN, (float*)d_out);
}